// Round 1
// baseline (928.303 us; speedup 1.0000x reference)
//
#include <hip/hip_runtime.h>
#include <math.h>

#define N_NODES  100000
#define N_HEDGES 100000
#define N_INC    1000000
#define IN_DIM   128

// ---------------------------------------------------------------------------
// W12[k][j] = sum_m W1[k][m] * W2[m][j]   (128x64 @ 64x3 -> 128x3)
// cvec[j]   = sum_m b1[m]   * W2[m][j]
__global__ void w12_kernel(const float* __restrict__ W1, const float* __restrict__ b1,
                           const float* __restrict__ W2, float* __restrict__ W12,
                           float* __restrict__ cvec) {
    int k = threadIdx.x;
    if (k < 128) {
        float a0 = 0.f, a1 = 0.f, a2 = 0.f;
        for (int m = 0; m < 64; ++m) {
            float w = W1[k * 64 + m];
            a0 += w * W2[m * 3 + 0];
            a1 += w * W2[m * 3 + 1];
            a2 += w * W2[m * 3 + 2];
        }
        W12[k * 3 + 0] = a0;
        W12[k * 3 + 1] = a1;
        W12[k * 3 + 2] = a2;
    }
    if (k < 3) {
        float c = 0.f;
        for (int m = 0; m < 64; ++m) c += b1[m] * W2[m * 3 + k];
        cvec[k] = c;
    }
}

// ---------------------------------------------------------------------------
// Z[n][0..2] = X[n][:] @ W12   — one wave per node, float2 per lane (coalesced)
__global__ void gemm_z_kernel(const float* __restrict__ X, const float* __restrict__ W12,
                              float* __restrict__ Z, int n_nodes) {
    __shared__ float w[IN_DIM * 3];
    int tid = threadIdx.x;
    for (int i = tid; i < IN_DIM * 3; i += blockDim.x) w[i] = W12[i];
    __syncthreads();

    int wave = tid >> 6;
    int lane = tid & 63;
    int node = blockIdx.x * 4 + wave;
    if (node >= n_nodes) return;

    float2 x2 = ((const float2*)(X + (size_t)node * IN_DIM))[lane];
    int k0 = 2 * lane, k1 = 2 * lane + 1;
    float a0 = x2.x * w[k0 * 3 + 0] + x2.y * w[k1 * 3 + 0];
    float a1 = x2.x * w[k0 * 3 + 1] + x2.y * w[k1 * 3 + 1];
    float a2 = x2.x * w[k0 * 3 + 2] + x2.y * w[k1 * 3 + 2];

    #pragma unroll
    for (int off = 32; off > 0; off >>= 1) {
        a0 += __shfl_xor(a0, off);
        a1 += __shfl_xor(a1, off);
        a2 += __shfl_xor(a2, off);
    }
    if (lane == 0) {
        Z[(size_t)node * 4 + 0] = a0;
        Z[(size_t)node * 4 + 1] = a1;
        Z[(size_t)node * 4 + 2] = a2;
        Z[(size_t)node * 4 + 3] = 0.f;
    }
}

// ---------------------------------------------------------------------------
__global__ void degrees_kernel(const int* __restrict__ ei0, const int* __restrict__ ei1,
                               float* __restrict__ D, float* __restrict__ B, int n) {
    int i = blockIdx.x * blockDim.x + threadIdx.x;
    if (i >= n) return;
    atomicAdd(&D[ei0[i]], 1.0f);
    atomicAdd(&B[ei1[i]], 1.0f);
}

// dst[idst[i]][j] += src[isrc[i]][j], j=0..2  (rows strided by 4 floats)
__global__ void scatter_kernel(const float* __restrict__ src, float* __restrict__ dst,
                               const int* __restrict__ isrc, const int* __restrict__ idst,
                               int n) {
    int i = blockIdx.x * blockDim.x + threadIdx.x;
    if (i >= n) return;
    int s = isrc[i], d = idst[i];
    float4 v = ((const float4*)src)[s];
    atomicAdd(&dst[(size_t)d * 4 + 0], v.x);
    atomicAdd(&dst[(size_t)d * 4 + 1], v.y);
    atomicAdd(&dst[(size_t)d * 4 + 2], v.z);
}

// arr[i][j] = arr[i][j] * (deg[i]>0 ? 1/deg[i] : 0) + (addv ? addv[j] : 0)
__global__ void scale_add_kernel(float* __restrict__ arr, const float* __restrict__ deg,
                                 const float* __restrict__ addv, int n) {
    int i = blockIdx.x * blockDim.x + threadIdx.x;
    if (i >= n) return;
    float dg = deg[i];
    float inv = dg > 0.f ? 1.0f / dg : 0.f;
    float a0 = 0.f, a1 = 0.f, a2 = 0.f;
    if (addv) { a0 = addv[0]; a1 = addv[1]; a2 = addv[2]; }
    arr[(size_t)i * 4 + 0] = arr[(size_t)i * 4 + 0] * inv + a0;
    arr[(size_t)i * 4 + 1] = arr[(size_t)i * 4 + 1] * inv + a1;
    arr[(size_t)i * 4 + 2] = arr[(size_t)i * 4 + 2] * inv + a2;
}

// per-hedge: mean -> sigmoid -> rowsum-normalize -> +gumbel -> argmax -> one-hot cols 0/2
__global__ void hedge_final_kernel(const float* __restrict__ XeC, const float* __restrict__ B,
                                   const float* __restrict__ gu, float* __restrict__ hard0,
                                   float* __restrict__ hard2, int n) {
    int h = blockIdx.x * blockDim.x + threadIdx.x;
    if (h >= n) return;
    float b = B[h];
    float binv = b > 0.f ? 1.0f / b : 0.f;
    float s0 = XeC[(size_t)h * 4 + 0] * binv;
    float s1 = XeC[(size_t)h * 4 + 1] * binv;
    float s2 = XeC[(size_t)h * 4 + 2] * binv;
    float x0 = 1.0f / (1.0f + expf(-s0));
    float x1 = 1.0f / (1.0f + expf(-s1));
    float x2 = 1.0f / (1.0f + expf(-s2));
    float rs = x0 + x1 + x2;
    float rinv = rs != 0.f ? 1.0f / rs : 0.f;
    x0 *= rinv; x1 *= rinv; x2 *= rinv;
    const float EPS = 1e-10f;
    float u0 = gu[(size_t)h * 3 + 0];
    float u1 = gu[(size_t)h * 3 + 1];
    float u2 = gu[(size_t)h * 3 + 2];
    float g0 = -logf(-logf(u0 + EPS) + EPS);
    float g1 = -logf(-logf(u1 + EPS) + EPS);
    float g2 = -logf(-logf(u2 + EPS) + EPS);
    // argmax(softmax(x)) == argmax(x); first-max wins like jnp.argmax
    float v0 = x0 + g0, v1 = x1 + g1, v2 = x2 + g2;
    int am = 0; float vm = v0;
    if (v1 > vm) { am = 1; vm = v1; }
    if (v2 > vm) { am = 2; vm = v2; }
    hard0[h] = (am == 0) ? 1.f : 0.f;
    hard2[h] = (am == 2) ? 1.f : 0.f;
}

// per-incidence: sample + masked edge_index (outputs as float per harness contract)
__global__ void edge_final_kernel(const float* __restrict__ hard0, const float* __restrict__ hard2,
                                  const float* __restrict__ ov,
                                  const int* __restrict__ ei0, const int* __restrict__ ei1,
                                  float* __restrict__ out, int n) {
    int i = blockIdx.x * blockDim.x + threadIdx.x;
    if (i >= n) return;
    int nn = ei0[i], hh = ei1[i];
    float r = hard0[hh];
    float m = hard2[hh] * (ov[nn] < 0.5f ? 1.f : 0.f);
    float s = fmaxf(r, m);
    out[i] = s;
    bool keep = s > 0.f;
    out[(size_t)N_INC + i]     = keep ? (float)nn : -1.f;
    out[(size_t)2 * N_INC + i] = keep ? (float)hh : -1.f;
}

// ---------------------------------------------------------------------------
extern "C" void kernel_launch(void* const* d_in, const int* in_sizes, int n_in,
                              void* d_out, int out_size, void* d_ws, size_t ws_size,
                              hipStream_t stream) {
    const float* X  = (const float*)d_in[0];
    const float* W1 = (const float*)d_in[1];
    const float* b1 = (const float*)d_in[2];
    const float* W2 = (const float*)d_in[3];
    const float* b2 = (const float*)d_in[4];
    const float* ov = (const float*)d_in[5];
    const float* gu = (const float*)d_in[6];
    const int*   ei = (const int*)d_in[7];
    const int* ei0 = ei;            // nodes
    const int* ei1 = ei + N_INC;    // hedges

    float* ws = (float*)d_ws;
    // zeroed region (accumulators + degrees), must be contiguous & first:
    float* B    = ws;                    // N_HEDGES
    float* D    = B    + N_HEDGES;       // N_NODES
    float* XeA  = D    + N_NODES;        // 4*N_HEDGES
    float* XnA  = XeA  + 4 * N_HEDGES;   // 4*N_NODES
    float* XeB  = XnA  + 4 * N_NODES;    // 4*N_HEDGES
    float* XnB  = XeB  + 4 * N_HEDGES;   // 4*N_NODES   (becomes H2 in-place)
    float* XeC  = XnB  + 4 * N_NODES;    // 4*N_HEDGES
    size_t zero_floats = (size_t)N_HEDGES + N_NODES
                       + 4ul * (3 * N_HEDGES + 2 * N_NODES);
    // non-zeroed scratch:
    float* Z     = XeC + 4 * N_HEDGES;   // 4*N_NODES
    float* hard0 = Z + 4 * N_NODES;      // N_HEDGES
    float* hard2 = hard0 + N_HEDGES;     // N_HEDGES
    float* W12   = hard2 + N_HEDGES;     // 384
    float* cvec  = W12 + 384;            // 3

    hipMemsetAsync(d_ws, 0, zero_floats * sizeof(float), stream);

    const int TB = 256;
    int gInc  = (N_INC + TB - 1) / TB;
    int gNode = (N_NODES + TB - 1) / TB;
    int gHed  = (N_HEDGES + TB - 1) / TB;

    w12_kernel<<<1, 128, 0, stream>>>(W1, b1, W2, W12, cvec);
    gemm_z_kernel<<<(N_NODES + 3) / 4, 256, 0, stream>>>(X, W12, Z, N_NODES);
    degrees_kernel<<<gInc, TB, 0, stream>>>(ei0, ei1, D, B, N_INC);

    // layer 1: Xe = Binv * segsum(Z[ei0] -> ei1); Xn = Dinv * segsum(Xe[ei1] -> ei0) + c
    scatter_kernel<<<gInc, TB, 0, stream>>>(Z, XeA, ei0, ei1, N_INC);
    scale_add_kernel<<<gHed, TB, 0, stream>>>(XeA, B, nullptr, N_HEDGES);
    scatter_kernel<<<gInc, TB, 0, stream>>>(XeA, XnA, ei1, ei0, N_INC);
    scale_add_kernel<<<gNode, TB, 0, stream>>>(XnA, D, cvec, N_NODES);   // Xt2 = L(Z)+c

    // layer 2: same operator on 3-wide rows; H2 = XnB*Dinv + b2 (in place)
    scatter_kernel<<<gInc, TB, 0, stream>>>(XnA, XeB, ei0, ei1, N_INC);
    scale_add_kernel<<<gHed, TB, 0, stream>>>(XeB, B, nullptr, N_HEDGES);
    scatter_kernel<<<gInc, TB, 0, stream>>>(XeB, XnB, ei1, ei0, N_INC);
    scale_add_kernel<<<gNode, TB, 0, stream>>>(XnB, D, b2, N_NODES);     // H2

    // scatter-mean of H2 into hedges (cnt == B), then sigmoid/normalize/gumbel/argmax
    scatter_kernel<<<gInc, TB, 0, stream>>>(XnB, XeC, ei0, ei1, N_INC);
    hedge_final_kernel<<<gHed, TB, 0, stream>>>(XeC, B, gu, hard0, hard2, N_HEDGES);

    edge_final_kernel<<<gInc, TB, 0, stream>>>(hard0, hard2, ov, ei0, ei1,
                                               (float*)d_out, N_INC);
}

// Round 2
// 234.401 us; speedup vs baseline: 3.9603x; 3.9603x over previous
//
#include <hip/hip_runtime.h>
#include <math.h>

#define N_NODES  100000
#define N_HEDGES 100000
#define N_INC    1000000
#define IN_DIM   128
#define SCAN_BS  512
#define NB_SCAN  ((N_NODES + SCAN_BS - 1) / SCAN_BS)   // 196 (nodes == hedges == 100k)

// ---------------------------------------------------------------------------
// W12 = W1 @ W2 (128x3), cvec = b1 @ W2 (3)
__global__ void w12_kernel(const float* __restrict__ W1, const float* __restrict__ b1,
                           const float* __restrict__ W2, float* __restrict__ W12,
                           float* __restrict__ cvec) {
    int k = threadIdx.x;
    if (k < 128) {
        float a0 = 0.f, a1 = 0.f, a2 = 0.f;
        for (int m = 0; m < 64; ++m) {
            float w = W1[k * 64 + m];
            a0 += w * W2[m * 3 + 0];
            a1 += w * W2[m * 3 + 1];
            a2 += w * W2[m * 3 + 2];
        }
        W12[k * 3 + 0] = a0;
        W12[k * 3 + 1] = a1;
        W12[k * 3 + 2] = a2;
    }
    if (k < 3) {
        float c = 0.f;
        for (int m = 0; m < 64; ++m) c += b1[m] * W2[m * 3 + k];
        cvec[k] = c;
    }
}

// ---------------------------------------------------------------------------
// Z[n][0..2] = X[n][:] @ W12 — one wave per node, float2 per lane
__global__ void gemm_z_kernel(const float* __restrict__ X, const float* __restrict__ W12,
                              float* __restrict__ Z, int n_nodes) {
    __shared__ float w[IN_DIM * 3];
    int tid = threadIdx.x;
    for (int i = tid; i < IN_DIM * 3; i += blockDim.x) w[i] = W12[i];
    __syncthreads();

    int wave = tid >> 6;
    int lane = tid & 63;
    int node = blockIdx.x * 4 + wave;
    if (node >= n_nodes) return;

    float2 x2 = ((const float2*)(X + (size_t)node * IN_DIM))[lane];
    int k0 = 2 * lane, k1 = 2 * lane + 1;
    float a0 = x2.x * w[k0 * 3 + 0] + x2.y * w[k1 * 3 + 0];
    float a1 = x2.x * w[k0 * 3 + 1] + x2.y * w[k1 * 3 + 1];
    float a2 = x2.x * w[k0 * 3 + 2] + x2.y * w[k1 * 3 + 2];

    #pragma unroll
    for (int off = 32; off > 0; off >>= 1) {
        a0 += __shfl_xor(a0, off);
        a1 += __shfl_xor(a1, off);
        a2 += __shfl_xor(a2, off);
    }
    if (lane == 0) {
        Z[(size_t)node * 4 + 0] = a0;
        Z[(size_t)node * 4 + 1] = a1;
        Z[(size_t)node * 4 + 2] = a2;
        Z[(size_t)node * 4 + 3] = 0.f;
    }
}

// ---------------------------------------------------------------------------
// CSR build step 1: per-incidence rank via fetch-add (counts == degrees)
__global__ void count_rank_kernel(const int* __restrict__ ei0, const int* __restrict__ ei1,
                                  int* __restrict__ cnt_n, int* __restrict__ cnt_h,
                                  int* __restrict__ rank_n, int* __restrict__ rank_h, int n) {
    int i = blockIdx.x * blockDim.x + threadIdx.x;
    if (i >= n) return;
    rank_n[i] = atomicAdd(&cnt_n[ei0[i]], 1);
    rank_h[i] = atomicAdd(&cnt_h[ei1[i]], 1);
}

// CSR build step 2a: per-block exclusive scan + block sums (both arrays via blockIdx.y)
__global__ void scan_block_kernel(const int* __restrict__ cnt_n, const int* __restrict__ cnt_h,
                                  int* __restrict__ off_n, int* __restrict__ off_h,
                                  int* __restrict__ part, int n) {
    __shared__ int s[SCAN_BS];
    const int* cnt = blockIdx.y ? cnt_h : cnt_n;
    int* off = blockIdx.y ? off_h : off_n;
    int tid = threadIdx.x;
    int i = blockIdx.x * SCAN_BS + tid;
    int v = (i < n) ? cnt[i] : 0;
    s[tid] = v;
    __syncthreads();
    for (int d = 1; d < SCAN_BS; d <<= 1) {
        int t = (tid >= d) ? s[tid - d] : 0;
        __syncthreads();
        s[tid] += t;
        __syncthreads();
    }
    if (i < n) off[i] = s[tid] - v;                 // exclusive prefix within block
    if (tid == SCAN_BS - 1) part[blockIdx.y * NB_SCAN + blockIdx.x] = s[tid];
}

// CSR build step 2b: scan the block sums (one block; NB_SCAN <= 256)
__global__ void scan_part_kernel(int* __restrict__ part) {
    __shared__ int s[256];
    int tid = threadIdx.x;
    for (int row = 0; row < 2; ++row) {
        int v = (tid < NB_SCAN) ? part[row * NB_SCAN + tid] : 0;
        s[tid] = v;
        __syncthreads();
        for (int d = 1; d < 256; d <<= 1) {
            int t = (tid >= d) ? s[tid - d] : 0;
            __syncthreads();
            s[tid] += t;
            __syncthreads();
        }
        if (tid < NB_SCAN) part[row * NB_SCAN + tid] = s[tid] - v;  // exclusive
        __syncthreads();
    }
}

// CSR build step 2c: add block offsets; write off[n] = N_INC
__global__ void scan_add_kernel(int* __restrict__ off_n, int* __restrict__ off_h,
                                const int* __restrict__ part, int n) {
    int* off = blockIdx.y ? off_h : off_n;
    int i = blockIdx.x * SCAN_BS + threadIdx.x;
    if (i < n) off[i] += part[blockIdx.y * NB_SCAN + blockIdx.x];
    if (i == 0) off[n] = N_INC;
}

// CSR build step 3: slot arrays hold the SOURCE row id for each gather
__global__ void build_slots_kernel(const int* __restrict__ ei0, const int* __restrict__ ei1,
                                   const int* __restrict__ rank_n, const int* __restrict__ rank_h,
                                   const int* __restrict__ off_n, const int* __restrict__ off_h,
                                   int* __restrict__ slot_n, int* __restrict__ slot_h, int n) {
    int i = blockIdx.x * blockDim.x + threadIdx.x;
    if (i >= n) return;
    int nn = ei0[i], hh = ei1[i];
    slot_n[off_n[nn] + rank_n[i]] = hh;   // node-gather sources = hedge ids
    slot_h[off_h[hh] + rank_h[i]] = nn;   // hedge-gather sources = node ids
}

// ---------------------------------------------------------------------------
// dst[r] = (1/deg) * sum_{j in seg(r)} src[slot[j]]  (+ addv), rows = 4 floats
__global__ void gather_kernel(const float* __restrict__ src, float* __restrict__ dst,
                              const int* __restrict__ off, const int* __restrict__ slot,
                              const float* __restrict__ addv, int nrows) {
    int r = blockIdx.x * blockDim.x + threadIdx.x;
    if (r >= nrows) return;
    int s = off[r], e = off[r + 1];
    float a0 = 0.f, a1 = 0.f, a2 = 0.f;
    for (int j = s; j < e; ++j) {
        float4 v = ((const float4*)src)[slot[j]];
        a0 += v.x; a1 += v.y; a2 += v.z;
    }
    float inv = (e > s) ? 1.0f / (float)(e - s) : 0.f;
    float b0 = 0.f, b1 = 0.f, b2 = 0.f;
    if (addv) { b0 = addv[0]; b1 = addv[1]; b2 = addv[2]; }
    ((float4*)dst)[r] = make_float4(a0 * inv + b0, a1 * inv + b1, a2 * inv + b2, 0.f);
}

// per-hedge: gather-mean of H2 -> sigmoid -> rowsum-normalize -> +gumbel -> argmax
__global__ void hedge_final_kernel(const float* __restrict__ H2,
                                   const int* __restrict__ off_h, const int* __restrict__ slot_h,
                                   const float* __restrict__ gu, float* __restrict__ hard0,
                                   float* __restrict__ hard2, int n) {
    int h = blockIdx.x * blockDim.x + threadIdx.x;
    if (h >= n) return;
    int s = off_h[h], e = off_h[h + 1];
    float a0 = 0.f, a1 = 0.f, a2 = 0.f;
    for (int j = s; j < e; ++j) {
        float4 v = ((const float4*)H2)[slot_h[j]];
        a0 += v.x; a1 += v.y; a2 += v.z;
    }
    float binv = (e > s) ? 1.0f / (float)(e - s) : 0.f;
    float s0 = a0 * binv, s1 = a1 * binv, s2 = a2 * binv;
    float x0 = 1.0f / (1.0f + expf(-s0));
    float x1 = 1.0f / (1.0f + expf(-s1));
    float x2 = 1.0f / (1.0f + expf(-s2));
    float rs = x0 + x1 + x2;
    float rinv = rs != 0.f ? 1.0f / rs : 0.f;
    x0 *= rinv; x1 *= rinv; x2 *= rinv;
    const float EPS = 1e-10f;
    float g0 = -logf(-logf(gu[(size_t)h * 3 + 0] + EPS) + EPS);
    float g1 = -logf(-logf(gu[(size_t)h * 3 + 1] + EPS) + EPS);
    float g2 = -logf(-logf(gu[(size_t)h * 3 + 2] + EPS) + EPS);
    // argmax(softmax(x)) == argmax(x); first-max wins like jnp.argmax
    float v0 = x0 + g0, v1 = x1 + g1, v2 = x2 + g2;
    int am = 0; float vm = v0;
    if (v1 > vm) { am = 1; vm = v1; }
    if (v2 > vm) { am = 2; vm = v2; }
    hard0[h] = (am == 0) ? 1.f : 0.f;
    hard2[h] = (am == 2) ? 1.f : 0.f;
}

// per-incidence: sample + masked edge_index
__global__ void edge_final_kernel(const float* __restrict__ hard0, const float* __restrict__ hard2,
                                  const float* __restrict__ ov,
                                  const int* __restrict__ ei0, const int* __restrict__ ei1,
                                  float* __restrict__ out, int n) {
    int i = blockIdx.x * blockDim.x + threadIdx.x;
    if (i >= n) return;
    int nn = ei0[i], hh = ei1[i];
    float r = hard0[hh];
    float m = hard2[hh] * (ov[nn] < 0.5f ? 1.f : 0.f);
    float s = fmaxf(r, m);
    out[i] = s;
    bool keep = s > 0.f;
    out[(size_t)N_INC + i]     = keep ? (float)nn : -1.f;
    out[(size_t)2 * N_INC + i] = keep ? (float)hh : -1.f;
}

// ---------------------------------------------------------------------------
extern "C" void kernel_launch(void* const* d_in, const int* in_sizes, int n_in,
                              void* d_out, int out_size, void* d_ws, size_t ws_size,
                              hipStream_t stream) {
    const float* X  = (const float*)d_in[0];
    const float* W1 = (const float*)d_in[1];
    const float* b1 = (const float*)d_in[2];
    const float* W2 = (const float*)d_in[3];
    const float* b2 = (const float*)d_in[4];
    const float* ov = (const float*)d_in[5];
    const float* gu = (const float*)d_in[6];
    const int*   ei = (const int*)d_in[7];
    const int* ei0 = ei;            // nodes
    const int* ei1 = ei + N_INC;    // hedges

    // ---- workspace layout (all sections multiple of 4 elems -> 16B aligned) ----
    int* ip = (int*)d_ws;
    int* cnt_n  = ip;                    // 100000  (zeroed)
    int* cnt_h  = cnt_n + N_NODES;       // 100000  (zeroed)
    int* off_n  = cnt_h + N_HEDGES;      // 100004
    int* off_h  = off_n + 100004;        // 100004
    int* part   = off_h + 100004;        // 400 (2 * NB_SCAN = 392, padded)
    int* rank_n = part + 400;            // 1M
    int* rank_h = rank_n + N_INC;        // 1M
    int* slot_n = rank_h + N_INC;        // 1M
    int* slot_h = slot_n + N_INC;        // 1M
    float* fp   = (float*)(slot_h + N_INC);
    float* Z     = fp;                   // 4*N_NODES
    float* XeA   = Z    + 4 * N_NODES;   // 4*N_HEDGES
    float* XnA   = XeA  + 4 * N_HEDGES;  // 4*N_NODES
    float* XeB   = XnA  + 4 * N_NODES;   // 4*N_HEDGES
    float* XnB   = XeB  + 4 * N_HEDGES;  // 4*N_NODES (= H2)
    float* hard0 = XnB  + 4 * N_NODES;   // N_HEDGES
    float* hard2 = hard0 + N_HEDGES;     // N_HEDGES
    float* W12   = hard2 + N_HEDGES;     // 384
    float* cvec  = W12 + 384;            // 4

    // only the counters need zeroing (gathers overwrite dst rows exactly once)
    hipMemsetAsync(cnt_n, 0, (size_t)(N_NODES + N_HEDGES) * sizeof(int), stream);

    const int TB = 256;
    int gInc  = (N_INC + TB - 1) / TB;
    int gHed  = (N_HEDGES + TB - 1) / TB;

    w12_kernel<<<1, 128, 0, stream>>>(W1, b1, W2, W12, cvec);
    gemm_z_kernel<<<(N_NODES + 3) / 4, 256, 0, stream>>>(X, W12, Z, N_NODES);

    // CSR build (both directions)
    count_rank_kernel<<<gInc, TB, 0, stream>>>(ei0, ei1, cnt_n, cnt_h, rank_n, rank_h, N_INC);
    scan_block_kernel<<<dim3(NB_SCAN, 2), SCAN_BS, 0, stream>>>(cnt_n, cnt_h, off_n, off_h, part, N_NODES);
    scan_part_kernel<<<1, 256, 0, stream>>>(part);
    scan_add_kernel<<<dim3(NB_SCAN, 2), SCAN_BS, 0, stream>>>(off_n, off_h, part, N_NODES);
    build_slots_kernel<<<gInc, TB, 0, stream>>>(ei0, ei1, rank_n, rank_h, off_n, off_h,
                                                slot_n, slot_h, N_INC);

    // layer 1: Xe = mean_hedge(Z); Xn = mean_node(Xe) + cvec
    gather_kernel<<<gHed, TB, 0, stream>>>(Z,   XeA, off_h, slot_h, nullptr, N_HEDGES);
    gather_kernel<<<gHed, TB, 0, stream>>>(XeA, XnA, off_n, slot_n, cvec,    N_NODES);
    // layer 2: H2 = mean_node(mean_hedge(XnA)) + b2
    gather_kernel<<<gHed, TB, 0, stream>>>(XnA, XeB, off_h, slot_h, nullptr, N_HEDGES);
    gather_kernel<<<gHed, TB, 0, stream>>>(XeB, XnB, off_n, slot_n, b2,      N_NODES);

    // scatter-mean of H2 into hedges fused with sigmoid/normalize/gumbel/argmax
    hedge_final_kernel<<<gHed, TB, 0, stream>>>(XnB, off_h, slot_h, gu, hard0, hard2, N_HEDGES);

    edge_final_kernel<<<gInc, TB, 0, stream>>>(hard0, hard2, ov, ei0, ei1,
                                               (float*)d_out, N_INC);
}

// Round 3
// 198.723 us; speedup vs baseline: 4.6714x; 1.1795x over previous
//
#include <hip/hip_runtime.h>
#include <math.h>

#define N_NODES  100000
#define N_HEDGES 100000
#define N_INC    1000000
#define IN_DIM   128

#define SHIFT    7
#define BMASK    127
#define NBKT     782        // ceil(100000/128); 782*128 = 100096
#define PH1_ITEMS 4096
#define NBLK     245        // ceil(1e6/4096)

typedef unsigned int u32;

// ---------------------------------------------------------------------------
// W12 = W1 @ W2 (128x3), cvec = b1 @ W2 (3)
__global__ void w12_kernel(const float* __restrict__ W1, const float* __restrict__ b1,
                           const float* __restrict__ W2, float* __restrict__ W12,
                           float* __restrict__ cvec) {
    int k = threadIdx.x;
    if (k < 128) {
        float a0 = 0.f, a1 = 0.f, a2 = 0.f;
        for (int m = 0; m < 64; ++m) {
            float w = W1[k * 64 + m];
            a0 += w * W2[m * 3 + 0];
            a1 += w * W2[m * 3 + 1];
            a2 += w * W2[m * 3 + 2];
        }
        W12[k * 3 + 0] = a0;
        W12[k * 3 + 1] = a1;
        W12[k * 3 + 2] = a2;
    }
    if (k < 3) {
        float c = 0.f;
        for (int m = 0; m < 64; ++m) c += b1[m] * W2[m * 3 + k];
        cvec[k] = c;
    }
}

// ---------------------------------------------------------------------------
// Z[n][0..2] = X[n][:] @ W12 — one wave per node, float2 per lane
__global__ void gemm_z_kernel(const float* __restrict__ X, const float* __restrict__ W12,
                              float* __restrict__ Z, int n_nodes) {
    __shared__ float w[IN_DIM * 3];
    int tid = threadIdx.x;
    for (int i = tid; i < IN_DIM * 3; i += blockDim.x) w[i] = W12[i];
    __syncthreads();

    int wave = tid >> 6;
    int lane = tid & 63;
    int node = blockIdx.x * 4 + wave;
    if (node >= n_nodes) return;

    float2 x2 = ((const float2*)(X + (size_t)node * IN_DIM))[lane];
    int k0 = 2 * lane, k1 = 2 * lane + 1;
    float a0 = x2.x * w[k0 * 3 + 0] + x2.y * w[k1 * 3 + 0];
    float a1 = x2.x * w[k0 * 3 + 1] + x2.y * w[k1 * 3 + 1];
    float a2 = x2.x * w[k0 * 3 + 2] + x2.y * w[k1 * 3 + 2];

    #pragma unroll
    for (int off = 32; off > 0; off >>= 1) {
        a0 += __shfl_xor(a0, off);
        a1 += __shfl_xor(a1, off);
        a2 += __shfl_xor(a2, off);
    }
    if (lane == 0) {
        Z[(size_t)node * 4 + 0] = a0;
        Z[(size_t)node * 4 + 1] = a1;
        Z[(size_t)node * 4 + 2] = a2;
        Z[(size_t)node * 4 + 3] = 0.f;
    }
}

// ---------------------------------------------------------------------------
// CSR build, atomic-free (LDS only).
// 1a: per-block LDS histograms over 782 coarse buckets (both directions);
//     tmp = (local_rank << 10) | bucket; hist rows written coalesced.
__global__ void bin_count_kernel(const int* __restrict__ ei0, const int* __restrict__ ei1,
                                 u32* __restrict__ tmp_n, u32* __restrict__ tmp_h,
                                 int* __restrict__ histmat) {
    __shared__ int hn[NBKT], hh[NBKT];
    int blk = blockIdx.x, t = threadIdx.x;
    for (int i = t; i < NBKT; i += 256) { hn[i] = 0; hh[i] = 0; }
    __syncthreads();
    int base = blk * PH1_ITEMS;
    #pragma unroll
    for (int k = 0; k < 16; ++k) {
        int i = base + t + k * 256;
        if (i < N_INC) {
            int n = ei0[i], h = ei1[i];
            int bn = n >> SHIFT, bh = h >> SHIFT;
            int rn = atomicAdd(&hn[bn], 1);
            int rh = atomicAdd(&hh[bh], 1);
            tmp_n[i] = ((u32)rn << 10) | (u32)bn;
            tmp_h[i] = ((u32)rh << 10) | (u32)bh;
        }
    }
    __syncthreads();
    for (int i = t; i < NBKT; i += 256) {
        histmat[blk * NBKT + i]          = hn[i];
        histmat[(NBLK + blk) * NBKT + i] = hh[i];
    }
}

// 1b: histmat[blk][bucket] -> global placement base (in place); bucket offsets out.
// grid = 2 (dir), 1024 threads. Column reads/writes are coalesced across threads.
__global__ void scan_kernel(int* __restrict__ histmat,
                            int* __restrict__ boff_n, int* __restrict__ boff_h,
                            int* __restrict__ off_n, int* __restrict__ off_h) {
    __shared__ int tot[1024];
    int dir = blockIdx.x, t = threadIdx.x;
    int* hm = histmat + (size_t)dir * NBLK * NBKT;
    int* boff = dir ? boff_h : boff_n;
    int* off  = dir ? off_h  : off_n;

    int sum = 0;
    if (t < NBKT) {
        for (int blk = 0; blk < NBLK; ++blk) {
            int v = hm[blk * NBKT + t];
            hm[blk * NBKT + t] = sum;
            sum += v;
        }
    }
    tot[t] = (t < NBKT) ? sum : 0;
    __syncthreads();
    for (int d = 1; d < 1024; d <<= 1) {
        int v = (t >= d) ? tot[t - d] : 0;
        __syncthreads();
        tot[t] += v;
        __syncthreads();
    }
    int excl = tot[t] - sum;   // exclusive prefix = bucket base
    if (t < NBKT) {
        boff[t] = excl;
        for (int blk = 0; blk < NBLK; ++blk) hm[blk * NBKT + t] += excl;
    }
    if (t == 0) { boff[NBKT] = N_INC; off[N_NODES] = N_INC; }
}

// 1c: place packed payload (dest_lo<<17 | src) into bucket-grouped order.
__global__ void place_kernel(const int* __restrict__ ei0, const int* __restrict__ ei1,
                             const u32* __restrict__ tmp_n, const u32* __restrict__ tmp_h,
                             const int* __restrict__ histmat,
                             u32* __restrict__ payload_n, u32* __restrict__ payload_h) {
    int blk = blockIdx.x, t = threadIdx.x;
    int base = blk * PH1_ITEMS;
    #pragma unroll
    for (int k = 0; k < 16; ++k) {
        int i = base + t + k * 256;
        if (i < N_INC) {
            int n = ei0[i], h = ei1[i];
            u32 tn = tmp_n[i], th = tmp_h[i];
            int bn = tn & 1023, rn = (int)(tn >> 10);
            int bh = th & 1023, rh = (int)(th >> 10);
            int pn = histmat[blk * NBKT + bn] + rn;
            int ph = histmat[(size_t)(NBLK + blk) * NBKT + bh] + rh;
            payload_n[pn] = ((u32)(n & BMASK) << 17) | (u32)h;   // node-CSR src = hedge
            payload_h[ph] = ((u32)(h & BMASK) << 17) | (u32)n;   // hedge-CSR src = node
        }
    }
}

// 2: per (bucket, dir): 128-bin LDS count + scan -> CSR off + dest-grouped slots.
__global__ void phase2_kernel(const u32* __restrict__ payload_n, const u32* __restrict__ payload_h,
                              const int* __restrict__ boff_n, const int* __restrict__ boff_h,
                              int* __restrict__ off_n, int* __restrict__ off_h,
                              int* __restrict__ slot_n, int* __restrict__ slot_h) {
    __shared__ int cnt[128], pre[128];
    int b = blockIdx.x, t = threadIdx.x;
    const u32* payload = blockIdx.y ? payload_h : payload_n;
    const int* boff    = blockIdx.y ? boff_h    : boff_n;
    int* off  = blockIdx.y ? off_h  : off_n;
    int* slot = blockIdx.y ? slot_h : slot_n;

    int base = boff[b], end = boff[b + 1];
    if (t < 128) cnt[t] = 0;
    __syncthreads();
    for (int j = base + t; j < end; j += 256) atomicAdd(&cnt[payload[j] >> 17], 1);
    __syncthreads();
    if (t < 128) pre[t] = cnt[t];
    __syncthreads();
    for (int d = 1; d < 128; d <<= 1) {
        int v = (t >= d && t < 128) ? pre[t - d] : 0;
        __syncthreads();
        if (t < 128) pre[t] += v;
        __syncthreads();
    }
    if (t < 128) {
        int e = pre[t] - cnt[t];           // exclusive
        int dest = (b << SHIFT) + t;
        if (dest < N_NODES) off[dest] = base + e;
        cnt[t] = e;                        // becomes cursor
    }
    __syncthreads();
    for (int j = base + t; j < end; j += 256) {
        u32 p = payload[j];
        int r = atomicAdd(&cnt[p >> 17], 1);
        slot[base + r] = (int)(p & 0x1FFFF);
    }
}

// ---------------------------------------------------------------------------
// dst[r] = (1/deg) * sum_{j in seg(r)} src[slot[j]]  (+ addv), rows = 4 floats
__global__ void gather_kernel(const float* __restrict__ src, float* __restrict__ dst,
                              const int* __restrict__ off, const int* __restrict__ slot,
                              const float* __restrict__ addv, int nrows) {
    int r = blockIdx.x * blockDim.x + threadIdx.x;
    if (r >= nrows) return;
    int s = off[r], e = off[r + 1];
    float a0 = 0.f, a1 = 0.f, a2 = 0.f;
    for (int j = s; j < e; ++j) {
        float4 v = ((const float4*)src)[slot[j]];
        a0 += v.x; a1 += v.y; a2 += v.z;
    }
    float inv = (e > s) ? 1.0f / (float)(e - s) : 0.f;
    float b0 = 0.f, b1 = 0.f, b2 = 0.f;
    if (addv) { b0 = addv[0]; b1 = addv[1]; b2 = addv[2]; }
    ((float4*)dst)[r] = make_float4(a0 * inv + b0, a1 * inv + b1, a2 * inv + b2, 0.f);
}

// per-hedge: gather-mean of H2 -> sigmoid -> rowsum-normalize -> +gumbel -> argmax
__global__ void hedge_final_kernel(const float* __restrict__ H2,
                                   const int* __restrict__ off_h, const int* __restrict__ slot_h,
                                   const float* __restrict__ gu, float* __restrict__ hard0,
                                   float* __restrict__ hard2, int n) {
    int h = blockIdx.x * blockDim.x + threadIdx.x;
    if (h >= n) return;
    int s = off_h[h], e = off_h[h + 1];
    float a0 = 0.f, a1 = 0.f, a2 = 0.f;
    for (int j = s; j < e; ++j) {
        float4 v = ((const float4*)H2)[slot_h[j]];
        a0 += v.x; a1 += v.y; a2 += v.z;
    }
    float binv = (e > s) ? 1.0f / (float)(e - s) : 0.f;
    float s0 = a0 * binv, s1 = a1 * binv, s2 = a2 * binv;
    float x0 = 1.0f / (1.0f + expf(-s0));
    float x1 = 1.0f / (1.0f + expf(-s1));
    float x2 = 1.0f / (1.0f + expf(-s2));
    float rs = x0 + x1 + x2;
    float rinv = rs != 0.f ? 1.0f / rs : 0.f;
    x0 *= rinv; x1 *= rinv; x2 *= rinv;
    const float EPS = 1e-10f;
    float g0 = -logf(-logf(gu[(size_t)h * 3 + 0] + EPS) + EPS);
    float g1 = -logf(-logf(gu[(size_t)h * 3 + 1] + EPS) + EPS);
    float g2 = -logf(-logf(gu[(size_t)h * 3 + 2] + EPS) + EPS);
    // argmax(softmax(x)) == argmax(x); first-max wins like jnp.argmax
    float v0 = x0 + g0, v1 = x1 + g1, v2 = x2 + g2;
    int am = 0; float vm = v0;
    if (v1 > vm) { am = 1; vm = v1; }
    if (v2 > vm) { am = 2; vm = v2; }
    hard0[h] = (am == 0) ? 1.f : 0.f;
    hard2[h] = (am == 2) ? 1.f : 0.f;
}

// per-incidence: sample + masked edge_index
__global__ void edge_final_kernel(const float* __restrict__ hard0, const float* __restrict__ hard2,
                                  const float* __restrict__ ov,
                                  const int* __restrict__ ei0, const int* __restrict__ ei1,
                                  float* __restrict__ out, int n) {
    int i = blockIdx.x * blockDim.x + threadIdx.x;
    if (i >= n) return;
    int nn = ei0[i], hh = ei1[i];
    float r = hard0[hh];
    float m = hard2[hh] * (ov[nn] < 0.5f ? 1.f : 0.f);
    float s = fmaxf(r, m);
    out[i] = s;
    bool keep = s > 0.f;
    out[(size_t)N_INC + i]     = keep ? (float)nn : -1.f;
    out[(size_t)2 * N_INC + i] = keep ? (float)hh : -1.f;
}

// ---------------------------------------------------------------------------
extern "C" void kernel_launch(void* const* d_in, const int* in_sizes, int n_in,
                              void* d_out, int out_size, void* d_ws, size_t ws_size,
                              hipStream_t stream) {
    const float* X  = (const float*)d_in[0];
    const float* W1 = (const float*)d_in[1];
    const float* b1 = (const float*)d_in[2];
    const float* W2 = (const float*)d_in[3];
    const float* b2 = (const float*)d_in[4];
    const float* ov = (const float*)d_in[5];
    const float* gu = (const float*)d_in[6];
    const int*   ei = (const int*)d_in[7];
    const int* ei0 = ei;            // nodes
    const int* ei1 = ei + N_INC;    // hedges

    // ---- workspace layout (ints; all section starts 16B aligned) ----
    int* ip = (int*)d_ws;
    u32* tmp_n     = (u32*)ip;                    // 1M   (dead after place)
    u32* tmp_h     = tmp_n + N_INC;               // 1M
    u32* payload_n = tmp_h + N_INC;               // 1M   (dead after phase2)
    u32* payload_h = payload_n + N_INC;           // 1M
    int* slot_n    = (int*)(payload_h + N_INC);   // 1M
    int* slot_h    = slot_n + N_INC;              // 1M
    int* off_n     = slot_h + N_INC;              // 100004
    int* off_h     = off_n + 100004;              // 100004
    int* histmat   = off_h + 100004;              // 2*NBLK*NBKT = 383180 -> 383200
    int* boff_n    = histmat + 383200;            // 784
    int* boff_h    = boff_n + 784;                // 784
    float* W12     = (float*)(boff_h + 784);      // 384
    float* cvec    = W12 + 384;                   // 4
    // float arrays alias the payload region (payload dead before gemm_z runs)
    float* Z     = (float*)payload_n;             // 400k
    float* XeA   = Z    + 4 * N_NODES;            // 400k
    float* XnA   = XeA  + 4 * N_HEDGES;           // 400k
    float* XeB   = XnA  + 4 * N_NODES;            // 400k
    float* XnB   = XeB  + 4 * N_HEDGES;           // 400k (= H2)
    // hard0/2 alias tmp region (tmp dead before hedge_final)
    float* hard0 = (float*)tmp_n;                 // 100k
    float* hard2 = hard0 + N_HEDGES;              // 100k

    const int TB = 256;
    int gInc = (N_INC + TB - 1) / TB;
    int gHed = (N_HEDGES + TB - 1) / TB;

    w12_kernel<<<1, 128, 0, stream>>>(W1, b1, W2, W12, cvec);

    // CSR build, atomic-free
    bin_count_kernel<<<NBLK, 256, 0, stream>>>(ei0, ei1, tmp_n, tmp_h, histmat);
    scan_kernel<<<2, 1024, 0, stream>>>(histmat, boff_n, boff_h, off_n, off_h);
    place_kernel<<<NBLK, 256, 0, stream>>>(ei0, ei1, tmp_n, tmp_h, histmat,
                                           payload_n, payload_h);
    phase2_kernel<<<dim3(NBKT, 2), 256, 0, stream>>>(payload_n, payload_h, boff_n, boff_h,
                                                     off_n, off_h, slot_n, slot_h);

    // dense projection (after phase2: payload region reused for Z..XnB)
    gemm_z_kernel<<<(N_NODES + 3) / 4, 256, 0, stream>>>(X, W12, Z, N_NODES);

    // layer 1: Xe = mean_hedge(Z); Xn = mean_node(Xe) + cvec
    gather_kernel<<<gHed, TB, 0, stream>>>(Z,   XeA, off_h, slot_h, nullptr, N_HEDGES);
    gather_kernel<<<gHed, TB, 0, stream>>>(XeA, XnA, off_n, slot_n, cvec,    N_NODES);
    // layer 2: H2 = mean_node(mean_hedge(XnA)) + b2
    gather_kernel<<<gHed, TB, 0, stream>>>(XnA, XeB, off_h, slot_h, nullptr, N_HEDGES);
    gather_kernel<<<gHed, TB, 0, stream>>>(XeB, XnB, off_n, slot_n, b2,      N_NODES);

    // scatter-mean of H2 into hedges fused with sigmoid/normalize/gumbel/argmax
    hedge_final_kernel<<<gHed, TB, 0, stream>>>(XnB, off_h, slot_h, gu, hard0, hard2, N_HEDGES);

    edge_final_kernel<<<gInc, TB, 0, stream>>>(hard0, hard2, ov, ei0, ei1,
                                               (float*)d_out, N_INC);
}